// Round 21
// baseline (131.668 us; speedup 1.0000x reference)
//
#include <hip/hip_runtime.h>
#include <stdint.h>

// B=2, L=2048, DIM=1024, 16 heads x 64
#define BATCH 2
#define SEQ   2048
#define DIM   1024
#define NH    16
#define MTOT  (BATCH*SEQ)   // 4096
#define LN_EPS 1e-5f
// Q scale folded with -log2(e): sigmoid(s) = rcp(1 + exp2(s*-log2e))
#define Q_FOLD_SCALE (-0.1803368801111204f)   // 0.125 * -1.4426950408889634

typedef __bf16 bf16x8 __attribute__((ext_vector_type(8)));
typedef float  f32x4  __attribute__((ext_vector_type(4)));

__device__ __forceinline__ unsigned short f2bf(float f) {
  uint32_t u = __float_as_uint(f);
  u += 0x7fffu + ((u >> 16) & 1u);      // RNE
  return (unsigned short)(u >> 16);
}
__device__ __forceinline__ unsigned short f2bf_rh(float f) {  // round-half-up (P>=0)
  uint32_t u = __float_as_uint(f) + 0x8000u;
  return (unsigned short)(u >> 16);
}

__device__ __forceinline__ void gload_lds16(const void* g, void* lds) {
  __builtin_amdgcn_global_load_lds(
      (const __attribute__((address_space(1))) uint32_t*)g,
      (__attribute__((address_space(3))) uint32_t*)lds, 16, 0, 0);
}

#define VMCNT(n) asm volatile("s_waitcnt vmcnt(" #n ")" ::: "memory")
#define BAR() do { __builtin_amdgcn_s_barrier(); __builtin_amdgcn_sched_barrier(0); } while (0)
// Barrier that also publishes this wave's ds_writes (lgkmcnt drain first).
#define BARW() do {                                           \
    asm volatile("s_waitcnt lgkmcnt(0)" ::: "memory");        \
    __builtin_amdgcn_s_barrier();                             \
    __builtin_amdgcn_sched_barrier(0);                        \
  } while (0)
// Fence between LDS writes and subsequent LDS reads of the same buffer.
#define DSFENCE() do {                                        \
    __builtin_amdgcn_sched_barrier(0);                        \
    asm volatile("s_waitcnt lgkmcnt(0)" ::: "memory");        \
    __builtin_amdgcn_sched_barrier(0);                        \
  } while (0)
#define ROT3(a, b, c) do { unsigned short* _t3 = (a); (a) = (b); (b) = (c); (c) = _t3; } while (0)
#define SWAP2(a, b) do { unsigned short* _t2 = (a); (a) = (b); (b) = _t2; } while (0)

// ---------------- f32 -> bf16 conversion (weights only) ----------------
__global__ void cvt_w_bf16(const float* __restrict__ s0, unsigned short* __restrict__ d0,
                           const float* __restrict__ s1, unsigned short* __restrict__ d1,
                           const float* __restrict__ s2, unsigned short* __restrict__ d2,
                           const float* __restrict__ s3, unsigned short* __restrict__ d3,
                           int n) {
  int z = blockIdx.y;
  const float* s = z == 0 ? s0 : z == 1 ? s1 : z == 2 ? s2 : s3;
  unsigned short* d = z == 0 ? d0 : z == 1 ? d1 : z == 2 ? d2 : d3;
  int i = (blockIdx.x * 256 + threadIdx.x) * 4;
  if (i >= n) return;
  float4 v = *(const float4*)(s + i);
  ushort4 o;
  o.x = f2bf(v.x); o.y = f2bf(v.y); o.z = f2bf(v.z); o.w = f2bf(v.w);
  *(ushort4*)(d + i) = o;
}

// ---------------- fused QKV projections, 512 threads (8 waves) ----------
// Block tile 128x128 unchanged (same traffic/LDS/swizzles/epilogue as R20);
// wave tile 32x64 (4 waves on M x 2 on N) -> 3 blocks/CU x 8 waves =
// 6 waves/SIMD (2x TLP vs the 256-thread version, which was grid-capped
// at 3 waves/SIMD with every pipe <25% busy = latency-bound).
// A (q/k/v f32) reg-staged + in-kernel RNE cvt -> LDS (bit-identical tiles);
// W gload_lds bf16. 2 A-chunks + 1 W load per thread/step -> VMCNT(3)/(0).
__global__ __launch_bounds__(512, 6)
void gemm_qkv(const float* __restrict__ Aq, const float* __restrict__ Ak,
              const float* __restrict__ Av,
              const unsigned short* __restrict__ Wqp, const unsigned short* __restrict__ Wkp,
              const unsigned short* __restrict__ Wvp,
              const float* __restrict__ gq, const float* __restrict__ bq,
              const float* __restrict__ gk, const float* __restrict__ bk,
              unsigned short* __restrict__ qh, unsigned short* __restrict__ kh,
              unsigned short* __restrict__ vT) {
  __shared__ unsigned short Asm[3][4096];  // [slot][row(128)][32] 8KB each
  __shared__ unsigned short Bsm[3][4096];
  const int z = blockIdx.z;
  const float* A = z == 0 ? Aq : z == 1 ? Ak : Av;
  const unsigned short* W = z == 0 ? Wqp : z == 1 ? Wkp : Wvp;
  const int t = threadIdx.x, w = t >> 6, l = t & 63, l15 = l & 15, lhi = l >> 4;
  const int wm = w >> 1, wn = w & 1;     // 4 waves on M, 2 on N
  const int m0 = blockIdx.x * 128, n0 = blockIdx.y * 128;
  const int sr0 = t >> 2, sc = (t & 3) ^ (((t >> 2) >> 1) & 3);  // W staging (rows 0..127)
  const int fsw = (l15 >> 1) & 3;          // frag-read XOR

  // A staging: chunk i = t + 512*j (j=0,1) -> row = i>>3 (0..127), c4 = i&7
  int aoffG[2], aoffL[2];
#pragma unroll
  for (int j = 0; j < 2; ++j) {
    int i = t + 512 * j, row = i >> 3, c4 = i & 7;
    aoffG[j] = row * 1024 + c4 * 4;
    aoffL[j] = row * 32 + (((c4 >> 1) ^ ((row >> 1) & 3)) * 8) + (c4 & 1) * 4;
  }

  unsigned short *ac = &Asm[0][0], *an = &Asm[1][0], *af_ = &Asm[2][0];
  unsigned short *bc = &Bsm[0][0], *bn = &Bsm[1][0], *bf_ = &Bsm[2][0];

  f32x4 acc[2][4] = {};
  float4 ra[2], rb[2];

#define LOADA(R, kt) do {                                                         \
    _Pragma("unroll")                                                             \
    for (int j = 0; j < 2; ++j)                                                   \
      R[j] = *(const float4*)(A + (size_t)m0 * 1024 + aoffG[j] + (kt) * 32);      \
  } while (0)
#define CVTA(R, sp) do {                                                          \
    _Pragma("unroll")                                                             \
    for (int j = 0; j < 2; ++j) {                                                 \
      ushort4 h;                                                                  \
      h.x = f2bf(R[j].x); h.y = f2bf(R[j].y);                                     \
      h.z = f2bf(R[j].z); h.w = f2bf(R[j].w);                                     \
      *(ushort4*)&(sp)[aoffL[j]] = h;                                             \
    }                                                                             \
  } while (0)
#define STAGE_W(bp, kt) do {                                                      \
    int k0 = (kt) * 32;                                                           \
    gload_lds16(W + (size_t)(n0 + sr0) * 1024 + k0 + sc * 8, (bp) + t * 8);       \
  } while (0)
#define COMPUTE() do {                                                            \
    bf16x8 afr[2], bfr[4];                                                        \
    _Pragma("unroll")                                                             \
    for (int mi = 0; mi < 2; ++mi)                                                \
      afr[mi] = *(const bf16x8*)&ac[(wm * 32 + mi * 16 + l15) * 32 + ((lhi ^ fsw) * 8)]; \
    _Pragma("unroll")                                                             \
    for (int ni = 0; ni < 4; ++ni)                                                \
      bfr[ni] = *(const bf16x8*)&bc[(wn * 64 + ni * 16 + l15) * 32 + ((lhi ^ fsw) * 8)]; \
    __builtin_amdgcn_s_setprio(1);                                                \
    _Pragma("unroll")                                                             \
    for (int mi = 0; mi < 2; ++mi)                                                \
      _Pragma("unroll")                                                           \
      for (int ni = 0; ni < 4; ++ni)                                              \
        acc[mi][ni] = __builtin_amdgcn_mfma_f32_16x16x32_bf16(afr[mi], bfr[ni], acc[mi][ni], 0, 0, 0); \
    __builtin_amdgcn_s_setprio(0);                                                \
  } while (0)
  // Step kt: issue A(kt+2)+W(kt+2); wait prior step's 3 loads; B1;
  // cvt A(kt+1) -> slot kt+1; compute kt; B2 (publishes ds_writes).
#define STEP(kt, RL, RC) do {                                                     \
    if ((kt) < 30) { LOADA(RL, (kt) + 2); STAGE_W(bf_, (kt) + 2); VMCNT(3); }     \
    else           { VMCNT(0); }                                                  \
    BARW();                                                                       \
    if ((kt) < 31) CVTA(RC, an);                                                  \
    COMPUTE();                                                                    \
    BARW();                                                                       \
    ROT3(ac, an, af_);                                                            \
    ROT3(bc, bn, bf_);                                                            \
  } while (0)

  // prologue: A(0)->ra, W(0); A(1)->rb, W(1); wait ra+W0; write Aslot0.
  LOADA(ra, 0); STAGE_W(bc, 0);
  LOADA(rb, 1); STAGE_W(bn, 1);
  VMCNT(3);
  CVTA(ra, ac);

  for (int kt2 = 0; kt2 < 16; ++kt2) {
    STEP(2 * kt2,     ra, rb);   // even: reload ra<-A(kt+2), cvt rb(=A(kt+1))
    STEP(2 * kt2 + 1, rb, ra);   // odd : reload rb,          cvt ra
  }
#undef STEP
#undef COMPUTE
#undef STAGE_W
#undef CVTA
#undef LOADA

  const int h = (n0 >> 6) + wn;  // wave's 64-col half = one head
  if (z == 2) {
#pragma unroll
    for (int mi = 0; mi < 2; ++mi)
#pragma unroll
      for (int r = 0; r < 4; ++r) {
        int gm = m0 + wm * 32 + mi * 16 + lhi * 4 + r;
        int b = gm >> 11, pos = gm & 2047;
#pragma unroll
        for (int ni = 0; ni < 4; ++ni)
          vT[(((size_t)(b * NH + h)) * 64 + ni * 16 + l15) * SEQ + pos] = f2bf(acc[mi][ni][r]);
      }
  } else {
    const float* G  = z ? gk : gq;
    const float* Bt = z ? bk : bq;
    unsigned short* outp = z ? kh : qh;
    const float scl = z ? 1.f : Q_FOLD_SCALE;
    float g[4], bt[4];
#pragma unroll
    for (int ni = 0; ni < 4; ++ni) { g[ni] = G[ni * 16 + l15]; bt[ni] = Bt[ni * 16 + l15]; }
#pragma unroll
    for (int mi = 0; mi < 2; ++mi)
#pragma unroll
      for (int r = 0; r < 4; ++r) {
        float x[4], s = 0.f, s2 = 0.f;
#pragma unroll
        for (int ni = 0; ni < 4; ++ni) { x[ni] = acc[mi][ni][r]; s += x[ni]; s2 += x[ni] * x[ni]; }
#pragma unroll
        for (int msk = 1; msk < 16; msk <<= 1) {
          s  += __shfl_xor(s,  msk, 64);
          s2 += __shfl_xor(s2, msk, 64);
        }
        float mu = s * (1.f / 64.f);
        float var = s2 * (1.f / 64.f) - mu * mu;
        float rstd = rsqrtf(var + LN_EPS);
        int gm = m0 + wm * 32 + mi * 16 + lhi * 4 + r;
        int b = gm >> 11, pos = gm & 2047;
        size_t base = (((size_t)(b * NH + h)) * SEQ + pos) * 64;
#pragma unroll
        for (int ni = 0; ni < 4; ++ni) {
          float y = ((x[ni] - mu) * rstd * g[ni] + bt[ni]) * scl;
          outp[base + ni * 16 + l15] = f2bf(y);
        }
      }
  }
}

// ---------------- out projection: out = x @ Wo^T + bo (f32) ----------------
// 128x64 tile, grid (32,16)=512 blocks = 2/CU; depth-2, 3 slots, 2 barriers.
__global__ __launch_bounds__(256, 3)
void gemm_out(const unsigned short* __restrict__ A, const unsigned short* __restrict__ W,
              const float* __restrict__ bias, float* __restrict__ outf) {
  __shared__ unsigned short Asm[3][4096];  // [slot][row(128)][32]
  __shared__ unsigned short Bsm[3][2048];  // [slot][row(64)][32]
  const int t = threadIdx.x, w = t >> 6, l = t & 63, l15 = l & 15, lhi = l >> 4;
  const int wm = w >> 1, wn = w & 1;
  const int m0 = blockIdx.x * 128, n0 = blockIdx.y * 64;
  const int sr0 = t >> 2, sc = (t & 3) ^ (((t >> 2) >> 1) & 3);
  const int fsw = (l15 >> 1) & 3;

  unsigned short *ac = &Asm[0][0], *an = &Asm[1][0], *af_ = &Asm[2][0];
  unsigned short *bc = &Bsm[0][0], *bn = &Bsm[1][0], *bf_ = &Bsm[2][0];
  f32x4 acc[4][2] = {};

#define STAGE_G(ap, bp, kt) do {                                                  \
    int k0 = (kt) * 32;                                                           \
    gload_lds16(A + (size_t)(m0 + sr0) * 1024 + k0 + sc * 8, (ap) + t * 8);       \
    gload_lds16(A + (size_t)(m0 + 64 + sr0) * 1024 + k0 + sc * 8,                 \
                (ap) + (t + 256) * 8);                                            \
    gload_lds16(W + (size_t)(n0 + sr0) * 1024 + k0 + sc * 8, (bp) + t * 8);       \
  } while (0)

  STAGE_G(ac, bc, 0);
  STAGE_G(an, bn, 1);
  for (int kt = 0; kt < 32; ++kt) {
    if (kt < 30)       { STAGE_G(af_, bf_, kt + 2); VMCNT(6); }
    else if (kt == 30) { VMCNT(3); }
    else               { VMCNT(0); }
    BAR();
    bf16x8 afr[4], bfr[2];
#pragma unroll
    for (int mi = 0; mi < 4; ++mi)
      afr[mi] = *(const bf16x8*)&ac[(wm * 64 + mi * 16 + l15) * 32 + ((lhi ^ fsw) * 8)];
#pragma unroll
    for (int ni = 0; ni < 2; ++ni)
      bfr[ni] = *(const bf16x8*)&bc[(wn * 32 + ni * 16 + l15) * 32 + ((lhi ^ fsw) * 8)];
    __builtin_amdgcn_s_setprio(1);
#pragma unroll
    for (int mi = 0; mi < 4; ++mi)
#pragma unroll
      for (int ni = 0; ni < 2; ++ni)
        acc[mi][ni] = __builtin_amdgcn_mfma_f32_16x16x32_bf16(afr[mi], bfr[ni], acc[mi][ni], 0, 0, 0);
    __builtin_amdgcn_s_setprio(0);
    BAR();
    ROT3(ac, an, af_);
    ROT3(bc, bn, bf_);
  }
#undef STAGE_G
  float bb[2];
#pragma unroll
  for (int ni = 0; ni < 2; ++ni) bb[ni] = bias[n0 + wn * 32 + ni * 16 + l15];
#pragma unroll
  for (int mi = 0; mi < 4; ++mi)
#pragma unroll
    for (int r = 0; r < 4; ++r) {
      int gm = m0 + wm * 64 + mi * 16 + lhi * 4 + r;
      float* op = outf + (size_t)gm * 1024 + n0 + wn * 32 + l15;
#pragma unroll
      for (int ni = 0; ni < 2; ++ni) op[ni * 16] = acc[mi][ni][r] + bb[ni];
    }
}

// ---------------- Sigmoid attention: 16 waves x 32 q-rows, KV parity split ---
// (R17-proven, ~57us)
__global__ __launch_bounds__(1024, 4)
void attn_kernel(const unsigned short* __restrict__ qh,
                 const unsigned short* __restrict__ kh,
                 const unsigned short* __restrict__ vT,
                 unsigned short* __restrict__ x) {
  __shared__ unsigned short SMEM[69632];   // [K 2buf x 2tile x 4096][V same][P 16x2304]
  const int t = threadIdx.x, w = t >> 6, l = t & 63, l15 = l & 15, lhi = l >> 4;
  const int g = w >> 3, wq = w & 7;
  const int L = blockIdx.x;               // 256 blocks
  const int xcd = L & 7, j = L >> 3;      // j in 0..31
  const int bh = xcd * 4 + (j >> 3);      // 4 heads per XCD
  const int qt = j & 7;                   // 8 q-tiles of 256
  const int b = bh >> 4;
  const unsigned short* Q = qh + (size_t)bh * SEQ * 64;
  const unsigned short* K = kh + (size_t)bh * SEQ * 64;
  const unsigned short* V = vT + (size_t)bh * 64 * SEQ;
  unsigned short* Pw = &SMEM[32768 + w * 2304];   // [32][72]
  const int qbase = qt * 256 + wq * 32;

  bf16x8 qf[2][2];
#pragma unroll
  for (int mi = 0; mi < 2; ++mi)
#pragma unroll
    for (int kb = 0; kb < 2; ++kb)
      qf[mi][kb] = *(const bf16x8*)&Q[(size_t)(qbase + mi * 16 + l15) * 64 + kb * 32 + lhi * 8];

  f32x4 o[2][4] = {};
  // staging coords: 1024 threads stage a 2-tile pair (parity p = t>>9)
  const int p = t >> 9, tid = t & 511, r0 = tid >> 3, c0 = tid & 7;

  unsigned short *kcur = &SMEM[0],     *knxt = &SMEM[8192];    // [buf: 2 tiles x 4096]
  unsigned short *vcur = &SMEM[16384], *vnxt = &SMEM[24576];

  // stage tile pair ts=(2*sp, 2*sp+1) into (kb_, vb_): this thread loads tile 2*sp+p
#define STAGE_PAIR(kb_, vb_, sp) do {                                                  \
    int kv0_ = (2 * (sp) + p) * 64;                                                    \
    gload_lds16(K + (size_t)(kv0_ + r0) * 64 + (c0 ^ (r0 & 7)) * 8,                    \
                (kb_) + p * 4096 + tid * 8);                                           \
    gload_lds16(V + (size_t)r0 * SEQ + kv0_ + (c0 ^ (r0 & 7)) * 8,                     \
                (vb_) + p * 4096 + tid * 8);                                           \
  } while (0)

  STAGE_PAIR(kcur, vcur, 0);
  for (int s = 0; s < 16; ++s) {
    if (s < 15) { STAGE_PAIR(knxt, vnxt, s + 1); VMCNT(2); }
    else        { VMCNT(0); }
    BAR();                        // cur pair valid for all waves

    const unsigned short* kc = kcur + g * 4096;   // this group's tile
    const unsigned short* vc = vcur + g * 4096;

    // QK^T (Q pre-scaled): s[mi][ni], row=q(mi*16+lhi*4+r), col=kv(ni*16+l15)
    f32x4 sS[2][4] = {};
    __builtin_amdgcn_s_setprio(1);
#pragma unroll
    for (int ni = 0; ni < 4; ++ni)
#pragma unroll
      for (int kb = 0; kb < 2; ++kb) {
        bf16x8 kfr = *(const bf16x8*)&kc[(ni * 16 + l15) * 64 + (((kb * 4 + lhi) ^ (l15 & 7)) * 8)];
        sS[0][ni] = __builtin_amdgcn_mfma_f32_16x16x32_bf16(qf[0][kb], kfr, sS[0][ni], 0, 0, 0);
        sS[1][ni] = __builtin_amdgcn_mfma_f32_16x16x32_bf16(qf[1][kb], kfr, sS[1][ni], 0, 0, 0);
      }
    __builtin_amdgcn_s_setprio(0);

    // sigmoid -> bf16 -> per-wave LDS
#pragma unroll
    for (int mi = 0; mi < 2; ++mi)
#pragma unroll
      for (int ni = 0; ni < 4; ++ni)
#pragma unroll
        for (int r = 0; r < 4; ++r) {
          float pv = __builtin_amdgcn_rcpf(1.0f + __builtin_amdgcn_exp2f(sS[mi][ni][r]));
          Pw[(mi * 16 + lhi * 4 + r) * 72 + ni * 16 + l15] = f2bf_rh(pv);
        }
    DSFENCE();                    // P writes complete before P reads

    // PV : O[32][64] += P[32][64] @ V[64][64]
    __builtin_amdgcn_s_setprio(1);
#pragma unroll
    for (int kq = 0; kq < 2; ++kq) {
      bf16x8 pf0 = *(const bf16x8*)&Pw[l15 * 72 + kq * 32 + lhi * 8];
      bf16x8 pf1 = *(const bf16x8*)&Pw[(16 + l15) * 72 + kq * 32 + lhi * 8];
#pragma unroll
      for (int di = 0; di < 4; ++di) {
        bf16x8 vfr = *(const bf16x8*)&vc[(di * 16 + l15) * 64 + (((kq * 4 + lhi) ^ (l15 & 7)) * 8)];
        o[0][di] = __builtin_amdgcn_mfma_f32_16x16x32_bf16(pf0, vfr, o[0][di], 0, 0, 0);
        o[1][di] = __builtin_amdgcn_mfma_f32_16x16x32_bf16(pf1, vfr, o[1][di], 0, 0, 0);
      }
    }
    __builtin_amdgcn_s_setprio(0);
    BAR();                        // readers done before buffer re-stage next step

    SWAP2(kcur, knxt);
    SWAP2(vcur, vnxt);
  }
#undef STAGE_PAIR

  // combine partial O across the two kv-parity groups via the dead K/V region
  float* Ob = (float*)SMEM;       // 8 waves x 2048 f32 = 64KB (K+V region)
  if (g == 1) {
#pragma unroll
    for (int mi = 0; mi < 2; ++mi)
#pragma unroll
      for (int di = 0; di < 4; ++di)
        *(f32x4*)&Ob[wq * 2048 + (mi * 4 + di) * 256 + l * 4] = o[mi][di];
  }
  DSFENCE();
  BAR();
  if (g == 0) {
#pragma unroll
    for (int mi = 0; mi < 2; ++mi)
#pragma unroll
      for (int di = 0; di < 4; ++di) {
        f32x4 op = *(const f32x4*)&Ob[wq * 2048 + (mi * 4 + di) * 256 + l * 4];
#pragma unroll
        for (int r = 0; r < 4; ++r) o[mi][di][r] += op[r];
      }
#pragma unroll
    for (int mi = 0; mi < 2; ++mi)
#pragma unroll
      for (int r = 0; r < 4; ++r) {
        int pos = qbase + mi * 16 + lhi * 4 + r;
        size_t base = ((size_t)b * SEQ + pos) * DIM + (bh & 15) * 64;
#pragma unroll
        for (int di = 0; di < 4; ++di)
          x[base + di * 16 + l15] = f2bf(o[mi][di][r]);
      }
  }
}

// ---------------- launch ----------------
extern "C" void kernel_launch(void* const* d_in, const int* in_sizes, int n_in,
                              void* d_out, int out_size, void* d_ws, size_t ws_size,
                              hipStream_t stream) {
  (void)in_sizes; (void)n_in; (void)out_size; (void)ws_size;
  const float* q  = (const float*)d_in[0];
  const float* k  = (const float*)d_in[1];
  const float* v  = (const float*)d_in[2];
  const float* Wq = (const float*)d_in[3];
  const float* Wk = (const float*)d_in[4];
  const float* Wv = (const float*)d_in[5];
  const float* gq = (const float*)d_in[6];
  const float* bq = (const float*)d_in[7];
  const float* gk = (const float*)d_in[8];
  const float* bk = (const float*)d_in[9];
  const float* Wo = (const float*)d_in[10];
  const float* bo = (const float*)d_in[11];
  float* out = (float*)d_out;

  char* ws = (char*)d_ws;
  const size_t MB = 1ull << 20;
  unsigned short* xb  = (unsigned short*)(ws + 0);        // [4096][1024] bf16
  unsigned short* Wqb = (unsigned short*)(ws + 24 * MB);
  unsigned short* Wkb = (unsigned short*)(ws + 26 * MB);
  unsigned short* Wvb = (unsigned short*)(ws + 28 * MB);
  unsigned short* Wob = (unsigned short*)(ws + 30 * MB);
  unsigned short* qhb = (unsigned short*)(ws + 32 * MB);  // [BH][L][64]
  unsigned short* khb = (unsigned short*)(ws + 40 * MB);  // [BH][L][64]
  unsigned short* vTb = (unsigned short*)(ws + 48 * MB);  // [BH][64][L]

  const int nW = DIM * DIM;     // 1,048,576

  cvt_w_bf16<<<dim3(nW / 1024, 4), 256, 0, stream>>>(Wq, Wqb, Wk, Wkb, Wv, Wvb, Wo, Wob, nW);

  gemm_qkv<<<dim3(MTOT / 128, DIM / 128, 3), 512, 0, stream>>>(q, k, v, Wqb, Wkb, Wvb,
                                                               gq, bq, gk, bk, qhb, khb, vTb);

  attn_kernel<<<dim3(256), 1024, 0, stream>>>(qhb, khb, vTb, xb);

  gemm_out<<<dim3(MTOT / 128, DIM / 64), 256, 0, stream>>>(xb, Wob, bo, out);
}

// Round 22
// 121.268 us; speedup vs baseline: 1.0858x; 1.0858x over previous
//
#include <hip/hip_runtime.h>
#include <stdint.h>

// B=2, L=2048, DIM=1024, 16 heads x 64
#define BATCH 2
#define SEQ   2048
#define DIM   1024
#define NH    16
#define MTOT  (BATCH*SEQ)   // 4096
#define LN_EPS 1e-5f
// Q scale folded with -log2(e): sigmoid(s) = rcp(1 + exp2(s*-log2e))
#define Q_FOLD_SCALE (-0.1803368801111204f)   // 0.125 * -1.4426950408889634

typedef __bf16 bf16x8 __attribute__((ext_vector_type(8)));
typedef float  f32x4  __attribute__((ext_vector_type(4)));

__device__ __forceinline__ unsigned short f2bf(float f) {
  uint32_t u = __float_as_uint(f);
  u += 0x7fffu + ((u >> 16) & 1u);      // RNE
  return (unsigned short)(u >> 16);
}
__device__ __forceinline__ unsigned short f2bf_rh(float f) {  // round-half-up (P>=0)
  uint32_t u = __float_as_uint(f) + 0x8000u;
  return (unsigned short)(u >> 16);
}

__device__ __forceinline__ void gload_lds16(const void* g, void* lds) {
  __builtin_amdgcn_global_load_lds(
      (const __attribute__((address_space(1))) uint32_t*)g,
      (__attribute__((address_space(3))) uint32_t*)lds, 16, 0, 0);
}

#define VMCNT(n) asm volatile("s_waitcnt vmcnt(" #n ")" ::: "memory")
#define BAR() do { __builtin_amdgcn_s_barrier(); __builtin_amdgcn_sched_barrier(0); } while (0)
// Barrier that also publishes this wave's ds_writes (lgkmcnt drain first).
#define BARW() do {                                           \
    asm volatile("s_waitcnt lgkmcnt(0)" ::: "memory");        \
    __builtin_amdgcn_s_barrier();                             \
    __builtin_amdgcn_sched_barrier(0);                        \
  } while (0)
// Fence between LDS writes and subsequent LDS reads of the same buffer.
#define DSFENCE() do {                                        \
    __builtin_amdgcn_sched_barrier(0);                        \
    asm volatile("s_waitcnt lgkmcnt(0)" ::: "memory");        \
    __builtin_amdgcn_sched_barrier(0);                        \
  } while (0)
#define ROT3(a, b, c) do { unsigned short* _t3 = (a); (a) = (b); (b) = (c); (c) = _t3; } while (0)
#define SWAP2(a, b) do { unsigned short* _t2 = (a); (a) = (b); (b) = _t2; } while (0)

// ---------------- f32 -> bf16 conversion (weights only) ----------------
__global__ void cvt_w_bf16(const float* __restrict__ s0, unsigned short* __restrict__ d0,
                           const float* __restrict__ s1, unsigned short* __restrict__ d1,
                           const float* __restrict__ s2, unsigned short* __restrict__ d2,
                           const float* __restrict__ s3, unsigned short* __restrict__ d3,
                           int n) {
  int z = blockIdx.y;
  const float* s = z == 0 ? s0 : z == 1 ? s1 : z == 2 ? s2 : s3;
  unsigned short* d = z == 0 ? d0 : z == 1 ? d1 : z == 2 ? d2 : d3;
  int i = (blockIdx.x * 256 + threadIdx.x) * 4;
  if (i >= n) return;
  float4 v = *(const float4*)(s + i);
  ushort4 o;
  o.x = f2bf(v.x); o.y = f2bf(v.y); o.z = f2bf(v.z); o.w = f2bf(v.w);
  *(ushort4*)(d + i) = o;
}

// ---------------- fused QKV projections with in-kernel A f32->bf16 ----------
// (R20-proven, best: 256 threads, 128x128 tile, 3 slots, depth-2, BARW x2)
__global__ __launch_bounds__(256, 3)
void gemm_qkv(const float* __restrict__ Aq, const float* __restrict__ Ak,
              const float* __restrict__ Av,
              const unsigned short* __restrict__ Wqp, const unsigned short* __restrict__ Wkp,
              const unsigned short* __restrict__ Wvp,
              const float* __restrict__ gq, const float* __restrict__ bq,
              const float* __restrict__ gk, const float* __restrict__ bk,
              unsigned short* __restrict__ qh, unsigned short* __restrict__ kh,
              unsigned short* __restrict__ vT) {
  __shared__ unsigned short Asm[3][4096];  // [slot][row(128)][32] 8KB each
  __shared__ unsigned short Bsm[3][4096];
  const int z = blockIdx.z;
  const float* A = z == 0 ? Aq : z == 1 ? Ak : Av;
  const unsigned short* W = z == 0 ? Wqp : z == 1 ? Wkp : Wvp;
  const int t = threadIdx.x, w = t >> 6, l = t & 63, l15 = l & 15, lhi = l >> 4;
  const int wm = w >> 1, wn = w & 1;
  const int m0 = blockIdx.x * 128, n0 = blockIdx.y * 128;
  const int sr0 = t >> 2, sc = (t & 3) ^ (((t >> 2) >> 1) & 3);
  const int fsw = (l15 >> 1) & 3;          // frag-read XOR

  // A staging coords: chunk i = t + 256*j -> row = i>>3, c4 = i&7 (16B f32 chunk)
  // LDS (elements): row*32 + ((c4>>1) ^ ((row>>1)&3))*8 + (c4&1)*4
  int aoffG[4], aoffL[4];
#pragma unroll
  for (int j = 0; j < 4; ++j) {
    int i = t + 256 * j, row = i >> 3, c4 = i & 7;
    aoffG[j] = row * 1024 + c4 * 4;
    aoffL[j] = row * 32 + (((c4 >> 1) ^ ((row >> 1) & 3)) * 8) + (c4 & 1) * 4;
  }

  unsigned short *ac = &Asm[0][0], *an = &Asm[1][0], *af_ = &Asm[2][0];
  unsigned short *bc = &Bsm[0][0], *bn = &Bsm[1][0], *bf_ = &Bsm[2][0];

  f32x4 acc[4][4] = {};
  float4 ra[4], rb[4];

#define LOADA(R, kt) do {                                                         \
    _Pragma("unroll")                                                             \
    for (int j = 0; j < 4; ++j)                                                   \
      R[j] = *(const float4*)(A + (size_t)m0 * 1024 + aoffG[j] + (kt) * 32);      \
  } while (0)
#define CVTA(R, sp) do {                                                          \
    _Pragma("unroll")                                                             \
    for (int j = 0; j < 4; ++j) {                                                 \
      ushort4 h;                                                                  \
      h.x = f2bf(R[j].x); h.y = f2bf(R[j].y);                                     \
      h.z = f2bf(R[j].z); h.w = f2bf(R[j].w);                                     \
      *(ushort4*)&(sp)[aoffL[j]] = h;                                             \
    }                                                                             \
  } while (0)
#define STAGE_W(bp, kt) do {                                                      \
    int k0 = (kt) * 32;                                                           \
    gload_lds16(W + (size_t)(n0 + sr0) * 1024 + k0 + sc * 8, (bp) + t * 8);       \
    gload_lds16(W + (size_t)(n0 + 64 + sr0) * 1024 + k0 + sc * 8,                 \
                (bp) + (t + 256) * 8);                                            \
  } while (0)
#define COMPUTE() do {                                                            \
    bf16x8 afr[4], bfr[4];                                                        \
    _Pragma("unroll")                                                             \
    for (int mi = 0; mi < 4; ++mi)                                                \
      afr[mi] = *(const bf16x8*)&ac[(wm * 64 + mi * 16 + l15) * 32 + ((lhi ^ fsw) * 8)]; \
    _Pragma("unroll")                                                             \
    for (int ni = 0; ni < 4; ++ni)                                                \
      bfr[ni] = *(const bf16x8*)&bc[(wn * 64 + ni * 16 + l15) * 32 + ((lhi ^ fsw) * 8)]; \
    __builtin_amdgcn_s_setprio(1);                                                \
    _Pragma("unroll")                                                             \
    for (int mi = 0; mi < 4; ++mi)                                                \
      _Pragma("unroll")                                                           \
      for (int ni = 0; ni < 4; ++ni)                                              \
        acc[mi][ni] = __builtin_amdgcn_mfma_f32_16x16x32_bf16(afr[mi], bfr[ni], acc[mi][ni], 0, 0, 0); \
    __builtin_amdgcn_s_setprio(0);                                                \
  } while (0)
  // Step kt: reload RL <- A(kt+2) + stage W(kt+2); wait prior step's 6 loads
  // (A-regs(kt+1) + W(kt+1)); B1; cvt RC (=A(kt+1)) -> slot kt+1; compute kt; B2.
#define STEP(kt, RL, RC) do {                                                     \
    if ((kt) < 30) { LOADA(RL, (kt) + 2); STAGE_W(bf_, (kt) + 2); VMCNT(6); }     \
    else           { VMCNT(0); }                                                  \
    BARW();                                                                       \
    if ((kt) < 31) CVTA(RC, an);                                                  \
    COMPUTE();                                                                    \
    BARW();                                                                       \
    ROT3(ac, an, af_);                                                            \
    ROT3(bc, bn, bf_);                                                            \
  } while (0)

  // prologue: A(0)->ra, W(0); A(1)->rb, W(1); wait ra+W0; write Aslot0.
  LOADA(ra, 0); STAGE_W(bc, 0);
  LOADA(rb, 1); STAGE_W(bn, 1);
  VMCNT(6);
  CVTA(ra, ac);

  for (int kt2 = 0; kt2 < 16; ++kt2) {
    STEP(2 * kt2,     ra, rb);   // even: reload ra<-A(kt+2), cvt rb(=A(kt+1))
    STEP(2 * kt2 + 1, rb, ra);   // odd : reload rb,          cvt ra
  }
#undef STEP
#undef COMPUTE
#undef STAGE_W
#undef CVTA
#undef LOADA

  const int h = (n0 >> 6) + wn;
  if (z == 2) {
#pragma unroll
    for (int mi = 0; mi < 4; ++mi)
#pragma unroll
      for (int r = 0; r < 4; ++r) {
        int gm = m0 + wm * 64 + mi * 16 + lhi * 4 + r;
        int b = gm >> 11, pos = gm & 2047;
#pragma unroll
        for (int ni = 0; ni < 4; ++ni)
          vT[(((size_t)(b * NH + h)) * 64 + ni * 16 + l15) * SEQ + pos] = f2bf(acc[mi][ni][r]);
      }
  } else {
    const float* G  = z ? gk : gq;
    const float* Bt = z ? bk : bq;
    unsigned short* outp = z ? kh : qh;
    const float scl = z ? 1.f : Q_FOLD_SCALE;
    float g[4], bt[4];
#pragma unroll
    for (int ni = 0; ni < 4; ++ni) { g[ni] = G[ni * 16 + l15]; bt[ni] = Bt[ni * 16 + l15]; }
#pragma unroll
    for (int mi = 0; mi < 4; ++mi)
#pragma unroll
      for (int r = 0; r < 4; ++r) {
        float x[4], s = 0.f, s2 = 0.f;
#pragma unroll
        for (int ni = 0; ni < 4; ++ni) { x[ni] = acc[mi][ni][r]; s += x[ni]; s2 += x[ni] * x[ni]; }
#pragma unroll
        for (int msk = 1; msk < 16; msk <<= 1) {
          s  += __shfl_xor(s,  msk, 64);
          s2 += __shfl_xor(s2, msk, 64);
        }
        float mu = s * (1.f / 64.f);
        float var = s2 * (1.f / 64.f) - mu * mu;
        float rstd = rsqrtf(var + LN_EPS);
        int gm = m0 + wm * 64 + mi * 16 + lhi * 4 + r;
        int b = gm >> 11, pos = gm & 2047;
        size_t base = (((size_t)(b * NH + h)) * SEQ + pos) * 64;
#pragma unroll
        for (int ni = 0; ni < 4; ++ni) {
          float y = ((x[ni] - mu) * rstd * g[ni] + bt[ni]) * scl;
          outp[base + ni * 16 + l15] = f2bf(y);
        }
      }
  }
}

// ---------------- out projection: out = x @ Wo^T + bo (f32) ----------------
// 128x64 tile, grid (32,16)=512 blocks = 2/CU; depth-2, 3 slots, 2 barriers.
__global__ __launch_bounds__(256, 3)
void gemm_out(const unsigned short* __restrict__ A, const unsigned short* __restrict__ W,
              const float* __restrict__ bias, float* __restrict__ outf) {
  __shared__ unsigned short Asm[3][4096];  // [slot][row(128)][32]
  __shared__ unsigned short Bsm[3][2048];  // [slot][row(64)][32]
  const int t = threadIdx.x, w = t >> 6, l = t & 63, l15 = l & 15, lhi = l >> 4;
  const int wm = w >> 1, wn = w & 1;
  const int m0 = blockIdx.x * 128, n0 = blockIdx.y * 64;
  const int sr0 = t >> 2, sc = (t & 3) ^ (((t >> 2) >> 1) & 3);
  const int fsw = (l15 >> 1) & 3;

  unsigned short *ac = &Asm[0][0], *an = &Asm[1][0], *af_ = &Asm[2][0];
  unsigned short *bc = &Bsm[0][0], *bn = &Bsm[1][0], *bf_ = &Bsm[2][0];
  f32x4 acc[4][2] = {};

#define STAGE_G(ap, bp, kt) do {                                                  \
    int k0 = (kt) * 32;                                                           \
    gload_lds16(A + (size_t)(m0 + sr0) * 1024 + k0 + sc * 8, (ap) + t * 8);       \
    gload_lds16(A + (size_t)(m0 + 64 + sr0) * 1024 + k0 + sc * 8,                 \
                (ap) + (t + 256) * 8);                                            \
    gload_lds16(W + (size_t)(n0 + sr0) * 1024 + k0 + sc * 8, (bp) + t * 8);       \
  } while (0)

  STAGE_G(ac, bc, 0);
  STAGE_G(an, bn, 1);
  for (int kt = 0; kt < 32; ++kt) {
    if (kt < 30)       { STAGE_G(af_, bf_, kt + 2); VMCNT(6); }
    else if (kt == 30) { VMCNT(3); }
    else               { VMCNT(0); }
    BAR();
    bf16x8 afr[4], bfr[2];
#pragma unroll
    for (int mi = 0; mi < 4; ++mi)
      afr[mi] = *(const bf16x8*)&ac[(wm * 64 + mi * 16 + l15) * 32 + ((lhi ^ fsw) * 8)];
#pragma unroll
    for (int ni = 0; ni < 2; ++ni)
      bfr[ni] = *(const bf16x8*)&bc[(wn * 32 + ni * 16 + l15) * 32 + ((lhi ^ fsw) * 8)];
    __builtin_amdgcn_s_setprio(1);
#pragma unroll
    for (int mi = 0; mi < 4; ++mi)
#pragma unroll
      for (int ni = 0; ni < 2; ++ni)
        acc[mi][ni] = __builtin_amdgcn_mfma_f32_16x16x32_bf16(afr[mi], bfr[ni], acc[mi][ni], 0, 0, 0);
    __builtin_amdgcn_s_setprio(0);
    BAR();
    ROT3(ac, an, af_);
    ROT3(bc, bn, bf_);
  }
#undef STAGE_G
  float bb[2];
#pragma unroll
  for (int ni = 0; ni < 2; ++ni) bb[ni] = bias[n0 + wn * 32 + ni * 16 + l15];
#pragma unroll
  for (int mi = 0; mi < 4; ++mi)
#pragma unroll
    for (int r = 0; r < 4; ++r) {
      int gm = m0 + wm * 64 + mi * 16 + lhi * 4 + r;
      float* op = outf + (size_t)gm * 1024 + n0 + wn * 32 + l15;
#pragma unroll
      for (int ni = 0; ni < 2; ++ni) op[ni * 16] = acc[mi][ni][r] + bb[ni];
    }
}

// ---------------- Sigmoid attention: 16 waves x 32 q-rows, KV parity split ---
// (R17-proven, ~57us)
__global__ __launch_bounds__(1024, 4)
void attn_kernel(const unsigned short* __restrict__ qh,
                 const unsigned short* __restrict__ kh,
                 const unsigned short* __restrict__ vT,
                 unsigned short* __restrict__ x) {
  __shared__ unsigned short SMEM[69632];   // [K 2buf x 2tile x 4096][V same][P 16x2304]
  const int t = threadIdx.x, w = t >> 6, l = t & 63, l15 = l & 15, lhi = l >> 4;
  const int g = w >> 3, wq = w & 7;
  const int L = blockIdx.x;               // 256 blocks
  const int xcd = L & 7, j = L >> 3;      // j in 0..31
  const int bh = xcd * 4 + (j >> 3);      // 4 heads per XCD
  const int qt = j & 7;                   // 8 q-tiles of 256
  const int b = bh >> 4;
  const unsigned short* Q = qh + (size_t)bh * SEQ * 64;
  const unsigned short* K = kh + (size_t)bh * SEQ * 64;
  const unsigned short* V = vT + (size_t)bh * 64 * SEQ;
  unsigned short* Pw = &SMEM[32768 + w * 2304];   // [32][72]
  const int qbase = qt * 256 + wq * 32;

  bf16x8 qf[2][2];
#pragma unroll
  for (int mi = 0; mi < 2; ++mi)
#pragma unroll
    for (int kb = 0; kb < 2; ++kb)
      qf[mi][kb] = *(const bf16x8*)&Q[(size_t)(qbase + mi * 16 + l15) * 64 + kb * 32 + lhi * 8];

  f32x4 o[2][4] = {};
  // staging coords: 1024 threads stage a 2-tile pair (parity p = t>>9)
  const int p = t >> 9, tid = t & 511, r0 = tid >> 3, c0 = tid & 7;

  unsigned short *kcur = &SMEM[0],     *knxt = &SMEM[8192];    // [buf: 2 tiles x 4096]
  unsigned short *vcur = &SMEM[16384], *vnxt = &SMEM[24576];

  // stage tile pair ts=(2*sp, 2*sp+1) into (kb_, vb_): this thread loads tile 2*sp+p
#define STAGE_PAIR(kb_, vb_, sp) do {                                                  \
    int kv0_ = (2 * (sp) + p) * 64;                                                    \
    gload_lds16(K + (size_t)(kv0_ + r0) * 64 + (c0 ^ (r0 & 7)) * 8,                    \
                (kb_) + p * 4096 + tid * 8);                                           \
    gload_lds16(V + (size_t)r0 * SEQ + kv0_ + (c0 ^ (r0 & 7)) * 8,                     \
                (vb_) + p * 4096 + tid * 8);                                           \
  } while (0)

  STAGE_PAIR(kcur, vcur, 0);
  for (int s = 0; s < 16; ++s) {
    if (s < 15) { STAGE_PAIR(knxt, vnxt, s + 1); VMCNT(2); }
    else        { VMCNT(0); }
    BAR();                        // cur pair valid for all waves

    const unsigned short* kc = kcur + g * 4096;   // this group's tile
    const unsigned short* vc = vcur + g * 4096;

    // QK^T (Q pre-scaled): s[mi][ni], row=q(mi*16+lhi*4+r), col=kv(ni*16+l15)
    f32x4 sS[2][4] = {};
    __builtin_amdgcn_s_setprio(1);
#pragma unroll
    for (int ni = 0; ni < 4; ++ni)
#pragma unroll
      for (int kb = 0; kb < 2; ++kb) {
        bf16x8 kfr = *(const bf16x8*)&kc[(ni * 16 + l15) * 64 + (((kb * 4 + lhi) ^ (l15 & 7)) * 8)];
        sS[0][ni] = __builtin_amdgcn_mfma_f32_16x16x32_bf16(qf[0][kb], kfr, sS[0][ni], 0, 0, 0);
        sS[1][ni] = __builtin_amdgcn_mfma_f32_16x16x32_bf16(qf[1][kb], kfr, sS[1][ni], 0, 0, 0);
      }
    __builtin_amdgcn_s_setprio(0);

    // sigmoid -> bf16 -> per-wave LDS
#pragma unroll
    for (int mi = 0; mi < 2; ++mi)
#pragma unroll
      for (int ni = 0; ni < 4; ++ni)
#pragma unroll
        for (int r = 0; r < 4; ++r) {
          float pv = __builtin_amdgcn_rcpf(1.0f + __builtin_amdgcn_exp2f(sS[mi][ni][r]));
          Pw[(mi * 16 + lhi * 4 + r) * 72 + ni * 16 + l15] = f2bf_rh(pv);
        }
    DSFENCE();                    // P writes complete before P reads

    // PV : O[32][64] += P[32][64] @ V[64][64]
    __builtin_amdgcn_s_setprio(1);
#pragma unroll
    for (int kq = 0; kq < 2; ++kq) {
      bf16x8 pf0 = *(const bf16x8*)&Pw[l15 * 72 + kq * 32 + lhi * 8];
      bf16x8 pf1 = *(const bf16x8*)&Pw[(16 + l15) * 72 + kq * 32 + lhi * 8];
#pragma unroll
      for (int di = 0; di < 4; ++di) {
        bf16x8 vfr = *(const bf16x8*)&vc[(di * 16 + l15) * 64 + (((kq * 4 + lhi) ^ (l15 & 7)) * 8)];
        o[0][di] = __builtin_amdgcn_mfma_f32_16x16x32_bf16(pf0, vfr, o[0][di], 0, 0, 0);
        o[1][di] = __builtin_amdgcn_mfma_f32_16x16x32_bf16(pf1, vfr, o[1][di], 0, 0, 0);
      }
    }
    __builtin_amdgcn_s_setprio(0);
    BAR();                        // readers done before buffer re-stage next step

    SWAP2(kcur, knxt);
    SWAP2(vcur, vnxt);
  }
#undef STAGE_PAIR

  // combine partial O across the two kv-parity groups via the dead K/V region
  float* Ob = (float*)SMEM;       // 8 waves x 2048 f32 = 64KB (K+V region)
  if (g == 1) {
#pragma unroll
    for (int mi = 0; mi < 2; ++mi)
#pragma unroll
      for (int di = 0; di < 4; ++di)
        *(f32x4*)&Ob[wq * 2048 + (mi * 4 + di) * 256 + l * 4] = o[mi][di];
  }
  DSFENCE();
  BAR();
  if (g == 0) {
#pragma unroll
    for (int mi = 0; mi < 2; ++mi)
#pragma unroll
      for (int di = 0; di < 4; ++di) {
        f32x4 op = *(const f32x4*)&Ob[wq * 2048 + (mi * 4 + di) * 256 + l * 4];
#pragma unroll
        for (int r = 0; r < 4; ++r) o[mi][di][r] += op[r];
      }
#pragma unroll
    for (int mi = 0; mi < 2; ++mi)
#pragma unroll
      for (int r = 0; r < 4; ++r) {
        int pos = qbase + mi * 16 + lhi * 4 + r;
        size_t base = ((size_t)b * SEQ + pos) * DIM + (bh & 15) * 64;
#pragma unroll
        for (int di = 0; di < 4; ++di)
          x[base + di * 16 + l15] = f2bf(o[mi][di][r]);
      }
  }
}

// ---------------- launch ----------------
extern "C" void kernel_launch(void* const* d_in, const int* in_sizes, int n_in,
                              void* d_out, int out_size, void* d_ws, size_t ws_size,
                              hipStream_t stream) {
  (void)in_sizes; (void)n_in; (void)out_size; (void)ws_size;
  const float* q  = (const float*)d_in[0];
  const float* k  = (const float*)d_in[1];
  const float* v  = (const float*)d_in[2];
  const float* Wq = (const float*)d_in[3];
  const float* Wk = (const float*)d_in[4];
  const float* Wv = (const float*)d_in[5];
  const float* gq = (const float*)d_in[6];
  const float* bq = (const float*)d_in[7];
  const float* gk = (const float*)d_in[8];
  const float* bk = (const float*)d_in[9];
  const float* Wo = (const float*)d_in[10];
  const float* bo = (const float*)d_in[11];
  float* out = (float*)d_out;

  char* ws = (char*)d_ws;
  const size_t MB = 1ull << 20;
  unsigned short* xb  = (unsigned short*)(ws + 0);        // [4096][1024] bf16
  unsigned short* Wqb = (unsigned short*)(ws + 24 * MB);
  unsigned short* Wkb = (unsigned short*)(ws + 26 * MB);
  unsigned short* Wvb = (unsigned short*)(ws + 28 * MB);
  unsigned short* Wob = (unsigned short*)(ws + 30 * MB);
  unsigned short* qhb = (unsigned short*)(ws + 32 * MB);  // [BH][L][64]
  unsigned short* khb = (unsigned short*)(ws + 40 * MB);  // [BH][L][64]
  unsigned short* vTb = (unsigned short*)(ws + 48 * MB);  // [BH][64][L]

  const int nW = DIM * DIM;     // 1,048,576

  cvt_w_bf16<<<dim3(nW / 1024, 4), 256, 0, stream>>>(Wq, Wqb, Wk, Wkb, Wv, Wvb, Wo, Wob, nW);

  gemm_qkv<<<dim3(MTOT / 128, DIM / 128, 3), 256, 0, stream>>>(q, k, v, Wqb, Wkb, Wvb,
                                                               gq, bq, gk, bk, qhb, khb, vTb);

  attn_kernel<<<dim3(256), 1024, 0, stream>>>(qhb, khb, vTb, xb);

  gemm_out<<<dim3(MTOT / 128, DIM / 64), 256, 0, stream>>>(xb, Wob, bo, out);
}

// Round 23
// 121.117 us; speedup vs baseline: 1.0871x; 1.0012x over previous
//
#include <hip/hip_runtime.h>
#include <stdint.h>

// B=2, L=2048, DIM=1024, 16 heads x 64
#define BATCH 2
#define SEQ   2048
#define DIM   1024
#define NH    16
#define MTOT  (BATCH*SEQ)   // 4096
#define LN_EPS 1e-5f
// Q scale folded with -log2(e): sigmoid(s) = rcp(1 + exp2(s*-log2e))
#define Q_FOLD_SCALE (-0.1803368801111204f)   // 0.125 * -1.4426950408889634

typedef __bf16 bf16x8 __attribute__((ext_vector_type(8)));
typedef float  f32x4  __attribute__((ext_vector_type(4)));

__device__ __forceinline__ unsigned short f2bf(float f) {
  uint32_t u = __float_as_uint(f);
  u += 0x7fffu + ((u >> 16) & 1u);      // RNE
  return (unsigned short)(u >> 16);
}
__device__ __forceinline__ unsigned short f2bf_rh(float f) {  // round-half-up (P>=0)
  uint32_t u = __float_as_uint(f) + 0x8000u;
  return (unsigned short)(u >> 16);
}

__device__ __forceinline__ void gload_lds16(const void* g, void* lds) {
  __builtin_amdgcn_global_load_lds(
      (const __attribute__((address_space(1))) uint32_t*)g,
      (__attribute__((address_space(3))) uint32_t*)lds, 16, 0, 0);
}

#define VMCNT(n) asm volatile("s_waitcnt vmcnt(" #n ")" ::: "memory")
#define BAR() do { __builtin_amdgcn_s_barrier(); __builtin_amdgcn_sched_barrier(0); } while (0)
// Barrier that also publishes this wave's ds_writes (lgkmcnt drain first).
#define BARW() do {                                           \
    asm volatile("s_waitcnt lgkmcnt(0)" ::: "memory");        \
    __builtin_amdgcn_s_barrier();                             \
    __builtin_amdgcn_sched_barrier(0);                        \
  } while (0)
// Fence between LDS writes and subsequent LDS reads of the same buffer.
#define DSFENCE() do {                                        \
    __builtin_amdgcn_sched_barrier(0);                        \
    asm volatile("s_waitcnt lgkmcnt(0)" ::: "memory");        \
    __builtin_amdgcn_sched_barrier(0);                        \
  } while (0)
#define ROT3(a, b, c) do { unsigned short* _t3 = (a); (a) = (b); (b) = (c); (c) = _t3; } while (0)
#define SWAP2(a, b) do { unsigned short* _t2 = (a); (a) = (b); (b) = _t2; } while (0)

// ---------------- f32 -> bf16 conversion (weights only) ----------------
__global__ void cvt_w_bf16(const float* __restrict__ s0, unsigned short* __restrict__ d0,
                           const float* __restrict__ s1, unsigned short* __restrict__ d1,
                           const float* __restrict__ s2, unsigned short* __restrict__ d2,
                           const float* __restrict__ s3, unsigned short* __restrict__ d3,
                           int n) {
  int z = blockIdx.y;
  const float* s = z == 0 ? s0 : z == 1 ? s1 : z == 2 ? s2 : s3;
  unsigned short* d = z == 0 ? d0 : z == 1 ? d1 : z == 2 ? d2 : d3;
  int i = (blockIdx.x * 256 + threadIdx.x) * 4;
  if (i >= n) return;
  float4 v = *(const float4*)(s + i);
  ushort4 o;
  o.x = f2bf(v.x); o.y = f2bf(v.y); o.z = f2bf(v.z); o.w = f2bf(v.w);
  *(ushort4*)(d + i) = o;
}

// ---------------- fused QKV projections with in-kernel A f32->bf16 ----------
// (R20/R22-proven best: 256 threads, 128x128 tile, 3 slots, depth-2, BARW x2)
__global__ __launch_bounds__(256, 3)
void gemm_qkv(const float* __restrict__ Aq, const float* __restrict__ Ak,
              const float* __restrict__ Av,
              const unsigned short* __restrict__ Wqp, const unsigned short* __restrict__ Wkp,
              const unsigned short* __restrict__ Wvp,
              const float* __restrict__ gq, const float* __restrict__ bq,
              const float* __restrict__ gk, const float* __restrict__ bk,
              unsigned short* __restrict__ qh, unsigned short* __restrict__ kh,
              unsigned short* __restrict__ vT) {
  __shared__ unsigned short Asm[3][4096];  // [slot][row(128)][32] 8KB each
  __shared__ unsigned short Bsm[3][4096];
  const int z = blockIdx.z;
  const float* A = z == 0 ? Aq : z == 1 ? Ak : Av;
  const unsigned short* W = z == 0 ? Wqp : z == 1 ? Wkp : Wvp;
  const int t = threadIdx.x, w = t >> 6, l = t & 63, l15 = l & 15, lhi = l >> 4;
  const int wm = w >> 1, wn = w & 1;
  const int m0 = blockIdx.x * 128, n0 = blockIdx.y * 128;
  const int sr0 = t >> 2, sc = (t & 3) ^ (((t >> 2) >> 1) & 3);
  const int fsw = (l15 >> 1) & 3;          // frag-read XOR

  // A staging coords: chunk i = t + 256*j -> row = i>>3, c4 = i&7 (16B f32 chunk)
  // LDS (elements): row*32 + ((c4>>1) ^ ((row>>1)&3))*8 + (c4&1)*4
  int aoffG[4], aoffL[4];
#pragma unroll
  for (int j = 0; j < 4; ++j) {
    int i = t + 256 * j, row = i >> 3, c4 = i & 7;
    aoffG[j] = row * 1024 + c4 * 4;
    aoffL[j] = row * 32 + (((c4 >> 1) ^ ((row >> 1) & 3)) * 8) + (c4 & 1) * 4;
  }

  unsigned short *ac = &Asm[0][0], *an = &Asm[1][0], *af_ = &Asm[2][0];
  unsigned short *bc = &Bsm[0][0], *bn = &Bsm[1][0], *bf_ = &Bsm[2][0];

  f32x4 acc[4][4] = {};
  float4 ra[4], rb[4];

#define LOADA(R, kt) do {                                                         \
    _Pragma("unroll")                                                             \
    for (int j = 0; j < 4; ++j)                                                   \
      R[j] = *(const float4*)(A + (size_t)m0 * 1024 + aoffG[j] + (kt) * 32);      \
  } while (0)
#define CVTA(R, sp) do {                                                          \
    _Pragma("unroll")                                                             \
    for (int j = 0; j < 4; ++j) {                                                 \
      ushort4 h;                                                                  \
      h.x = f2bf(R[j].x); h.y = f2bf(R[j].y);                                     \
      h.z = f2bf(R[j].z); h.w = f2bf(R[j].w);                                     \
      *(ushort4*)&(sp)[aoffL[j]] = h;                                             \
    }                                                                             \
  } while (0)
#define STAGE_W(bp, kt) do {                                                      \
    int k0 = (kt) * 32;                                                           \
    gload_lds16(W + (size_t)(n0 + sr0) * 1024 + k0 + sc * 8, (bp) + t * 8);       \
    gload_lds16(W + (size_t)(n0 + 64 + sr0) * 1024 + k0 + sc * 8,                 \
                (bp) + (t + 256) * 8);                                            \
  } while (0)
#define COMPUTE() do {                                                            \
    bf16x8 afr[4], bfr[4];                                                        \
    _Pragma("unroll")                                                             \
    for (int mi = 0; mi < 4; ++mi)                                                \
      afr[mi] = *(const bf16x8*)&ac[(wm * 64 + mi * 16 + l15) * 32 + ((lhi ^ fsw) * 8)]; \
    _Pragma("unroll")                                                             \
    for (int ni = 0; ni < 4; ++ni)                                                \
      bfr[ni] = *(const bf16x8*)&bc[(wn * 64 + ni * 16 + l15) * 32 + ((lhi ^ fsw) * 8)]; \
    __builtin_amdgcn_s_setprio(1);                                                \
    _Pragma("unroll")                                                             \
    for (int mi = 0; mi < 4; ++mi)                                                \
      _Pragma("unroll")                                                           \
      for (int ni = 0; ni < 4; ++ni)                                              \
        acc[mi][ni] = __builtin_amdgcn_mfma_f32_16x16x32_bf16(afr[mi], bfr[ni], acc[mi][ni], 0, 0, 0); \
    __builtin_amdgcn_s_setprio(0);                                                \
  } while (0)
  // Step kt: reload RL <- A(kt+2) + stage W(kt+2); wait prior step's 6 loads
  // (A-regs(kt+1) + W(kt+1)); B1; cvt RC (=A(kt+1)) -> slot kt+1; compute kt; B2.
#define STEP(kt, RL, RC) do {                                                     \
    if ((kt) < 30) { LOADA(RL, (kt) + 2); STAGE_W(bf_, (kt) + 2); VMCNT(6); }     \
    else           { VMCNT(0); }                                                  \
    BARW();                                                                       \
    if ((kt) < 31) CVTA(RC, an);                                                  \
    COMPUTE();                                                                    \
    BARW();                                                                       \
    ROT3(ac, an, af_);                                                            \
    ROT3(bc, bn, bf_);                                                            \
  } while (0)

  // prologue: A(0)->ra, W(0); A(1)->rb, W(1); wait ra+W0; write Aslot0.
  LOADA(ra, 0); STAGE_W(bc, 0);
  LOADA(rb, 1); STAGE_W(bn, 1);
  VMCNT(6);
  CVTA(ra, ac);

  for (int kt2 = 0; kt2 < 16; ++kt2) {
    STEP(2 * kt2,     ra, rb);   // even: reload ra<-A(kt+2), cvt rb(=A(kt+1))
    STEP(2 * kt2 + 1, rb, ra);   // odd : reload rb,          cvt ra
  }
#undef STEP
#undef COMPUTE
#undef STAGE_W
#undef CVTA
#undef LOADA

  const int h = (n0 >> 6) + wn;
  if (z == 2) {
#pragma unroll
    for (int mi = 0; mi < 4; ++mi)
#pragma unroll
      for (int r = 0; r < 4; ++r) {
        int gm = m0 + wm * 64 + mi * 16 + lhi * 4 + r;
        int b = gm >> 11, pos = gm & 2047;
#pragma unroll
        for (int ni = 0; ni < 4; ++ni)
          vT[(((size_t)(b * NH + h)) * 64 + ni * 16 + l15) * SEQ + pos] = f2bf(acc[mi][ni][r]);
      }
  } else {
    const float* G  = z ? gk : gq;
    const float* Bt = z ? bk : bq;
    unsigned short* outp = z ? kh : qh;
    const float scl = z ? 1.f : Q_FOLD_SCALE;
    float g[4], bt[4];
#pragma unroll
    for (int ni = 0; ni < 4; ++ni) { g[ni] = G[ni * 16 + l15]; bt[ni] = Bt[ni * 16 + l15]; }
#pragma unroll
    for (int mi = 0; mi < 4; ++mi)
#pragma unroll
      for (int r = 0; r < 4; ++r) {
        float x[4], s = 0.f, s2 = 0.f;
#pragma unroll
        for (int ni = 0; ni < 4; ++ni) { x[ni] = acc[mi][ni][r]; s += x[ni]; s2 += x[ni] * x[ni]; }
#pragma unroll
        for (int msk = 1; msk < 16; msk <<= 1) {
          s  += __shfl_xor(s,  msk, 64);
          s2 += __shfl_xor(s2, msk, 64);
        }
        float mu = s * (1.f / 64.f);
        float var = s2 * (1.f / 64.f) - mu * mu;
        float rstd = rsqrtf(var + LN_EPS);
        int gm = m0 + wm * 64 + mi * 16 + lhi * 4 + r;
        int b = gm >> 11, pos = gm & 2047;
        size_t base = (((size_t)(b * NH + h)) * SEQ + pos) * 64;
#pragma unroll
        for (int ni = 0; ni < 4; ++ni) {
          float y = ((x[ni] - mu) * rstd * g[ni] + bt[ni]) * scl;
          outp[base + ni * 16 + l15] = f2bf(y);
        }
      }
  }
}

// ---------------- out projection: out = x @ Wo^T + bo (f32) ----------------
// 128x64 tile, grid (32,16)=512 blocks = 2/CU; depth-2, 3 slots, 2 barriers.
__global__ __launch_bounds__(256, 3)
void gemm_out(const unsigned short* __restrict__ A, const unsigned short* __restrict__ W,
              const float* __restrict__ bias, float* __restrict__ outf) {
  __shared__ unsigned short Asm[3][4096];  // [slot][row(128)][32]
  __shared__ unsigned short Bsm[3][2048];  // [slot][row(64)][32]
  const int t = threadIdx.x, w = t >> 6, l = t & 63, l15 = l & 15, lhi = l >> 4;
  const int wm = w >> 1, wn = w & 1;
  const int m0 = blockIdx.x * 128, n0 = blockIdx.y * 64;
  const int sr0 = t >> 2, sc = (t & 3) ^ (((t >> 2) >> 1) & 3);
  const int fsw = (l15 >> 1) & 3;

  unsigned short *ac = &Asm[0][0], *an = &Asm[1][0], *af_ = &Asm[2][0];
  unsigned short *bc = &Bsm[0][0], *bn = &Bsm[1][0], *bf_ = &Bsm[2][0];
  f32x4 acc[4][2] = {};

#define STAGE_G(ap, bp, kt) do {                                                  \
    int k0 = (kt) * 32;                                                           \
    gload_lds16(A + (size_t)(m0 + sr0) * 1024 + k0 + sc * 8, (ap) + t * 8);       \
    gload_lds16(A + (size_t)(m0 + 64 + sr0) * 1024 + k0 + sc * 8,                 \
                (ap) + (t + 256) * 8);                                            \
    gload_lds16(W + (size_t)(n0 + sr0) * 1024 + k0 + sc * 8, (bp) + t * 8);       \
  } while (0)

  STAGE_G(ac, bc, 0);
  STAGE_G(an, bn, 1);
  for (int kt = 0; kt < 32; ++kt) {
    if (kt < 30)       { STAGE_G(af_, bf_, kt + 2); VMCNT(6); }
    else if (kt == 30) { VMCNT(3); }
    else               { VMCNT(0); }
    BAR();
    bf16x8 afr[4], bfr[2];
#pragma unroll
    for (int mi = 0; mi < 4; ++mi)
      afr[mi] = *(const bf16x8*)&ac[(wm * 64 + mi * 16 + l15) * 32 + ((lhi ^ fsw) * 8)];
#pragma unroll
    for (int ni = 0; ni < 2; ++ni)
      bfr[ni] = *(const bf16x8*)&bc[(wn * 32 + ni * 16 + l15) * 32 + ((lhi ^ fsw) * 8)];
    __builtin_amdgcn_s_setprio(1);
#pragma unroll
    for (int mi = 0; mi < 4; ++mi)
#pragma unroll
      for (int ni = 0; ni < 2; ++ni)
        acc[mi][ni] = __builtin_amdgcn_mfma_f32_16x16x32_bf16(afr[mi], bfr[ni], acc[mi][ni], 0, 0, 0);
    __builtin_amdgcn_s_setprio(0);
    BAR();
    ROT3(ac, an, af_);
    ROT3(bc, bn, bf_);
  }
#undef STAGE_G
  float bb[2];
#pragma unroll
  for (int ni = 0; ni < 2; ++ni) bb[ni] = bias[n0 + wn * 32 + ni * 16 + l15];
#pragma unroll
  for (int mi = 0; mi < 4; ++mi)
#pragma unroll
    for (int r = 0; r < 4; ++r) {
      int gm = m0 + wm * 64 + mi * 16 + lhi * 4 + r;
      float* op = outf + (size_t)gm * 1024 + n0 + wn * 32 + l15;
#pragma unroll
      for (int ni = 0; ni < 2; ++ni) op[ni * 16] = acc[mi][ni][r] + bb[ni];
    }
}

// ---------------- Sigmoid attention: 16 waves x 32 q-rows, KV parity split ---
// (R17-proven, ~57us)
__global__ __launch_bounds__(1024, 4)
void attn_kernel(const unsigned short* __restrict__ qh,
                 const unsigned short* __restrict__ kh,
                 const unsigned short* __restrict__ vT,
                 unsigned short* __restrict__ x) {
  __shared__ unsigned short SMEM[69632];   // [K 2buf x 2tile x 4096][V same][P 16x2304]
  const int t = threadIdx.x, w = t >> 6, l = t & 63, l15 = l & 15, lhi = l >> 4;
  const int g = w >> 3, wq = w & 7;
  const int L = blockIdx.x;               // 256 blocks
  const int xcd = L & 7, j = L >> 3;      // j in 0..31
  const int bh = xcd * 4 + (j >> 3);      // 4 heads per XCD
  const int qt = j & 7;                   // 8 q-tiles of 256
  const int b = bh >> 4;
  const unsigned short* Q = qh + (size_t)bh * SEQ * 64;
  const unsigned short* K = kh + (size_t)bh * SEQ * 64;
  const unsigned short* V = vT + (size_t)bh * 64 * SEQ;
  unsigned short* Pw = &SMEM[32768 + w * 2304];   // [32][72]
  const int qbase = qt * 256 + wq * 32;

  bf16x8 qf[2][2];
#pragma unroll
  for (int mi = 0; mi < 2; ++mi)
#pragma unroll
    for (int kb = 0; kb < 2; ++kb)
      qf[mi][kb] = *(const bf16x8*)&Q[(size_t)(qbase + mi * 16 + l15) * 64 + kb * 32 + lhi * 8];

  f32x4 o[2][4] = {};
  // staging coords: 1024 threads stage a 2-tile pair (parity p = t>>9)
  const int p = t >> 9, tid = t & 511, r0 = tid >> 3, c0 = tid & 7;

  unsigned short *kcur = &SMEM[0],     *knxt = &SMEM[8192];    // [buf: 2 tiles x 4096]
  unsigned short *vcur = &SMEM[16384], *vnxt = &SMEM[24576];

  // stage tile pair ts=(2*sp, 2*sp+1) into (kb_, vb_): this thread loads tile 2*sp+p
#define STAGE_PAIR(kb_, vb_, sp) do {                                                  \
    int kv0_ = (2 * (sp) + p) * 64;                                                    \
    gload_lds16(K + (size_t)(kv0_ + r0) * 64 + (c0 ^ (r0 & 7)) * 8,                    \
                (kb_) + p * 4096 + tid * 8);                                           \
    gload_lds16(V + (size_t)r0 * SEQ + kv0_ + (c0 ^ (r0 & 7)) * 8,                     \
                (vb_) + p * 4096 + tid * 8);                                           \
  } while (0)

  STAGE_PAIR(kcur, vcur, 0);
  for (int s = 0; s < 16; ++s) {
    if (s < 15) { STAGE_PAIR(knxt, vnxt, s + 1); VMCNT(2); }
    else        { VMCNT(0); }
    BAR();                        // cur pair valid for all waves

    const unsigned short* kc = kcur + g * 4096;   // this group's tile
    const unsigned short* vc = vcur + g * 4096;

    // QK^T (Q pre-scaled): s[mi][ni], row=q(mi*16+lhi*4+r), col=kv(ni*16+l15)
    f32x4 sS[2][4] = {};
    __builtin_amdgcn_s_setprio(1);
#pragma unroll
    for (int ni = 0; ni < 4; ++ni)
#pragma unroll
      for (int kb = 0; kb < 2; ++kb) {
        bf16x8 kfr = *(const bf16x8*)&kc[(ni * 16 + l15) * 64 + (((kb * 4 + lhi) ^ (l15 & 7)) * 8)];
        sS[0][ni] = __builtin_amdgcn_mfma_f32_16x16x32_bf16(qf[0][kb], kfr, sS[0][ni], 0, 0, 0);
        sS[1][ni] = __builtin_amdgcn_mfma_f32_16x16x32_bf16(qf[1][kb], kfr, sS[1][ni], 0, 0, 0);
      }
    __builtin_amdgcn_s_setprio(0);

    // sigmoid -> bf16 -> per-wave LDS
#pragma unroll
    for (int mi = 0; mi < 2; ++mi)
#pragma unroll
      for (int ni = 0; ni < 4; ++ni)
#pragma unroll
        for (int r = 0; r < 4; ++r) {
          float pv = __builtin_amdgcn_rcpf(1.0f + __builtin_amdgcn_exp2f(sS[mi][ni][r]));
          Pw[(mi * 16 + lhi * 4 + r) * 72 + ni * 16 + l15] = f2bf_rh(pv);
        }
    DSFENCE();                    // P writes complete before P reads

    // PV : O[32][64] += P[32][64] @ V[64][64]
    __builtin_amdgcn_s_setprio(1);
#pragma unroll
    for (int kq = 0; kq < 2; ++kq) {
      bf16x8 pf0 = *(const bf16x8*)&Pw[l15 * 72 + kq * 32 + lhi * 8];
      bf16x8 pf1 = *(const bf16x8*)&Pw[(16 + l15) * 72 + kq * 32 + lhi * 8];
#pragma unroll
      for (int di = 0; di < 4; ++di) {
        bf16x8 vfr = *(const bf16x8*)&vc[(di * 16 + l15) * 64 + (((kq * 4 + lhi) ^ (l15 & 7)) * 8)];
        o[0][di] = __builtin_amdgcn_mfma_f32_16x16x32_bf16(pf0, vfr, o[0][di], 0, 0, 0);
        o[1][di] = __builtin_amdgcn_mfma_f32_16x16x32_bf16(pf1, vfr, o[1][di], 0, 0, 0);
      }
    }
    __builtin_amdgcn_s_setprio(0);
    BAR();                        // readers done before buffer re-stage next step

    SWAP2(kcur, knxt);
    SWAP2(vcur, vnxt);
  }
#undef STAGE_PAIR

  // combine partial O across the two kv-parity groups via the dead K/V region
  float* Ob = (float*)SMEM;       // 8 waves x 2048 f32 = 64KB (K+V region)
  if (g == 1) {
#pragma unroll
    for (int mi = 0; mi < 2; ++mi)
#pragma unroll
      for (int di = 0; di < 4; ++di)
        *(f32x4*)&Ob[wq * 2048 + (mi * 4 + di) * 256 + l * 4] = o[mi][di];
  }
  DSFENCE();
  BAR();
  if (g == 0) {
#pragma unroll
    for (int mi = 0; mi < 2; ++mi)
#pragma unroll
      for (int di = 0; di < 4; ++di) {
        f32x4 op = *(const f32x4*)&Ob[wq * 2048 + (mi * 4 + di) * 256 + l * 4];
#pragma unroll
        for (int r = 0; r < 4; ++r) o[mi][di][r] += op[r];
      }
#pragma unroll
    for (int mi = 0; mi < 2; ++mi)
#pragma unroll
      for (int r = 0; r < 4; ++r) {
        int pos = qbase + mi * 16 + lhi * 4 + r;
        size_t base = ((size_t)b * SEQ + pos) * DIM + (bh & 15) * 64;
#pragma unroll
        for (int di = 0; di < 4; ++di)
          x[base + di * 16 + l15] = f2bf(o[mi][di][r]);
      }
  }
}

// ---------------- launch ----------------
extern "C" void kernel_launch(void* const* d_in, const int* in_sizes, int n_in,
                              void* d_out, int out_size, void* d_ws, size_t ws_size,
                              hipStream_t stream) {
  (void)in_sizes; (void)n_in; (void)out_size; (void)ws_size;
  const float* q  = (const float*)d_in[0];
  const float* k  = (const float*)d_in[1];
  const float* v  = (const float*)d_in[2];
  const float* Wq = (const float*)d_in[3];
  const float* Wk = (const float*)d_in[4];
  const float* Wv = (const float*)d_in[5];
  const float* gq = (const float*)d_in[6];
  const float* bq = (const float*)d_in[7];
  const float* gk = (const float*)d_in[8];
  const float* bk = (const float*)d_in[9];
  const float* Wo = (const float*)d_in[10];
  const float* bo = (const float*)d_in[11];
  float* out = (float*)d_out;

  char* ws = (char*)d_ws;
  const size_t MB = 1ull << 20;
  unsigned short* xb  = (unsigned short*)(ws + 0);        // [4096][1024] bf16
  unsigned short* Wqb = (unsigned short*)(ws + 24 * MB);
  unsigned short* Wkb = (unsigned short*)(ws + 26 * MB);
  unsigned short* Wvb = (unsigned short*)(ws + 28 * MB);
  unsigned short* Wob = (unsigned short*)(ws + 30 * MB);
  unsigned short* qhb = (unsigned short*)(ws + 32 * MB);  // [BH][L][64]
  unsigned short* khb = (unsigned short*)(ws + 40 * MB);  // [BH][L][64]
  unsigned short* vTb = (unsigned short*)(ws + 48 * MB);  // [BH][64][L]

  const int nW = DIM * DIM;     // 1,048,576

  cvt_w_bf16<<<dim3(nW / 1024, 4), 256, 0, stream>>>(Wq, Wqb, Wk, Wkb, Wv, Wvb, Wo, Wob, nW);

  gemm_qkv<<<dim3(MTOT / 128, DIM / 128, 3), 256, 0, stream>>>(q, k, v, Wqb, Wkb, Wvb,
                                                               gq, bq, gk, bk, qhb, khb, vTb);

  attn_kernel<<<dim3(256), 1024, 0, stream>>>(qhb, khb, vTb, xb);

  gemm_out<<<dim3(MTOT / 128, DIM / 64), 256, 0, stream>>>(xb, Wob, bo, out);
}